// Round 12
// baseline (184.031 us; speedup 1.0000x reference)
//
#include <hip/hip_runtime.h>

// ============ MEASUREMENT ROUND: prep launched 4x (idempotent) ============
// total = base + 3 * prep_warm  -> direct attribution of prep_kernel.
// Kernel bodies are byte-identical to the R10 best (101.1 us).

typedef __attribute__((ext_vector_type(8))) short bf16x8;
typedef __attribute__((ext_vector_type(4))) float f32x4;
typedef __attribute__((ext_vector_type(4))) unsigned short us4;

#define E_DIM 100
#define L_SEQ 20
#define NV    30000
#define NVP   30080
#define MROWS 2000
#define KP    128
#define KW    112       // whh padded K
#define WSTR  53        // W1/W2 LDS row stride in float4

__device__ inline unsigned short f2bf(float f){
  unsigned int u = __float_as_uint(f);
  return (unsigned short)((u + 0x7fffu + ((u>>16)&1u)) >> 16);
}
__device__ inline float dot4(float4 a, float4 b){
  return a.x*b.x + a.y*b.y + a.z*b.z + a.w*b.w;
}
__device__ inline void store4bf(unsigned short* dst, float4 x){
  us4 p = { f2bf(x.x), f2bf(x.y), f2bf(x.z), f2bf(x.w) };
  *(us4*)dst = p;
}
__device__ inline float fsig(float x){
  float t = __builtin_amdgcn_exp2f(x * -1.44269504f);
  return __builtin_amdgcn_rcpf(1.f + t);
}
__device__ inline float ftanh(float x){
  float cx = fminf(fmaxf(x, -15.f), 15.f);
  float t = __builtin_amdgcn_exp2f(cx * 2.88539008f);
  return (t - 1.f) * __builtin_amdgcn_rcpf(t + 1.f);
}

// ---------------- G: build all bf16 operands (pure streaming) ----------------
#define C1     962560
#define C2    1044480
#define C3    1060864
#define C4    1072064
#define C5    1072576
__global__ void gather_kernel(const int* __restrict__ seq, const int* __restrict__ ss2,
    const float* __restrict__ item, const float* __restrict__ W_ih,
    const float* __restrict__ W_hh, const float* __restrict__ b_ih,
    const float* __restrict__ b_hh,
    unsigned short* __restrict__ ib, unsigned short* __restrict__ xg,
    unsigned short* __restrict__ wihb, unsigned short* __restrict__ whhb,
    float* __restrict__ biasv){
  int id = blockIdx.x*256 + threadIdx.x;
  if (id < C1){
    int v = id >> 5, k4 = (id & 31) << 2;
    float4 x = {0.f,0.f,0.f,0.f};
    if (v < NV && k4 < 100) x = *(const float4*)(item + (size_t)v*E_DIM + k4);
    store4bf(ib + (size_t)v*KP + k4, x);
  } else if (id < C2){
    int idx = id - C1;
    int m = idx >> 5, k4 = (idx & 31) << 2;
    int src = -1;
    if (m < MROWS) src = seq[m];
    else if (m >= 2048 && m < 2548) src = ss2[(m-2048)*L_SEQ];
    float4 x = {0.f,0.f,0.f,0.f};
    if (src >= 0 && k4 < 100) x = *(const float4*)(item + (size_t)src*E_DIM + k4);
    store4bf(xg + (size_t)m*KP + k4, x);
  } else if (id < C3){
    int idx = id - C2;
    int j = idx >> 5, k4 = (idx & 31) << 2;
    float4 x = {0.f,0.f,0.f,0.f};
    if (j < 400 && k4 < 100) x = *(const float4*)(W_ih + (size_t)j*E_DIM + k4);
    store4bf(wihb + (size_t)j*KP + k4, x);
  } else if (id < C4){
    int idx = id - C3;
    int j = idx / 28, k4 = (idx - j*28) << 2;
    float4 x = {0.f,0.f,0.f,0.f};
    if (k4 < 100) x = *(const float4*)(W_hh + (size_t)j*E_DIM + k4);
    store4bf(whhb + (size_t)j*KW + k4, x);
  } else if (id < C5){
    int n = id - C4;
    biasv[n] = (n < 400) ? (b_ih[n] + b_hh[n]) : 0.f;
  }
}

// ---------------- GX: gx[m][n] = xg[m] . wihb[n] + biasv[n] (MFMA) ----------------
__global__ __launch_bounds__(256) void gxgemm_kernel(
    const unsigned short* __restrict__ xg, const unsigned short* __restrict__ wihb,
    const float* __restrict__ biasv, float* __restrict__ gx){
  __shared__ unsigned short As[128*KP];
  __shared__ unsigned short Bs[128*KP];
  int tile_m = blockIdx.x >> 2;
  int tile_n = blockIdx.x & 3;
  int tid = threadIdx.x;
  const float4* Ag = (const float4*)(xg   + (size_t)tile_m*128*KP);
  const float4* Bg = (const float4*)(wihb + (size_t)tile_n*128*KP);
  float4* As4=(float4*)As; float4* Bs4=(float4*)Bs;
#pragma unroll
  for (int i=0;i<8;i++){
    int chunk = i*256 + tid;
    int row = chunk >> 4;
    int cb  = (chunk & 15) << 4;
    int sw  = cb ^ ((row & 7) << 4);
    int di  = row*16 + (sw >> 4);
    As4[di] = Ag[chunk];
    Bs4[di] = Bg[chunk];
  }
  __syncthreads();
  int wave = tid >> 6, lane = tid & 63;
  int wm = (wave >> 1) << 6, wn = (wave & 1) << 6;
  int lrow = lane & 15, lq = lane >> 4;
  f32x4 acc[4][4];
#pragma unroll
  for (int i=0;i<4;i++)
#pragma unroll
    for (int jj=0;jj<4;jj++) acc[i][jj] = (f32x4){0.f,0.f,0.f,0.f};
#pragma unroll
  for (int kk=0;kk<4;kk++){
    int koffb = (kk*32 + lq*8) * 2;
    bf16x8 a[4], bfr[4];
#pragma unroll
    for (int i=0;i<4;i++){
      int row = wm + i*16 + lrow;
      int boff = koffb ^ ((row & 7) << 4);
      a[i] = *(const bf16x8*)(As + row*KP + (boff >> 1));
    }
#pragma unroll
    for (int jj=0;jj<4;jj++){
      int row = wn + jj*16 + lrow;
      int boff = koffb ^ ((row & 7) << 4);
      bfr[jj] = *(const bf16x8*)(Bs + row*KP + (boff >> 1));
    }
#pragma unroll
    for (int i=0;i<4;i++)
#pragma unroll
      for (int jj=0;jj<4;jj++)
        acc[i][jj] = __builtin_amdgcn_mfma_f32_16x16x32_bf16(bfr[jj], a[i], acc[i][jj], 0, 0, 0);
  }
  int n0 = tile_n*128 + wn + lq*4;
  int m0 = tile_m*128 + wm + lrow;
#pragma unroll
  for (int i=0;i<4;i++){
    int m = m0 + i*16;
#pragma unroll
    for (int jj=0;jj<4;jj++){
      int n = n0 + jj*16;
      if (n < 400){
        float4 bv = *(const float4*)(biasv + n);
        *(float4*)(gx + (size_t)m*400 + n) =
          (float4){acc[i][jj][0]+bv.x, acc[i][jj][1]+bv.y, acc[i][jj][2]+bv.z, acc[i][jj][3]+bv.w};
      }
    }
  }
}

// ---------------- PREP (R10 exact): MFMA recurrence; W1/W2 LDS-staged ----------
__global__ __launch_bounds__(512,1) void prep_kernel(
    const int* __restrict__ sn2, const int* __restrict__ mask,
    const float* __restrict__ user, const float* __restrict__ W1,
    const float* __restrict__ W2, const float* __restrict__ Wg0,
    const unsigned short* __restrict__ whhb, const float* __restrict__ gx,
    unsigned short* __restrict__ srb){
  int b = blockIdx.x, tid = threadIdx.x;
  int wave = tid >> 6, lane = tid & 63;
  int lrow = lane & 15, lq = lane >> 4;
  __shared__ float4 Wsh[100*WSTR];       // 84,800 B: W1, then W2 (restaged)
  __shared__ float  gxl[L_SEQ][400];     // 32,000 B
  __shared__ unsigned short hsb[128];
  __shared__ float  gsh[400];
  __shared__ float4 hu4[L_SEQ][25];
  __shared__ float4 stcat4[5][50];
  __shared__ float  ls2l[5][100];
  __shared__ float  ns[6][100];
  __shared__ float  wsc[8];
  __shared__ float  ctx[100];
  __shared__ float4 h04[25];

  // stage gx rows for this block (2000 float4, coalesced) + W1 -> LDS
  {
    const float4* src = (const float4*)(gx + (size_t)b*L_SEQ*400);
    for (int u = tid; u < 2000; u += 512) ((float4*)gxl)[u] = src[u];
    const float4* w1g = (const float4*)W1;           // 100 rows x 50 f4
    for (int u = tid; u < 5000; u += 512){
      int r = u / 50, cc = u - r*50;
      Wsh[r*WSTR + cc] = w1g[u];
    }
  }
  if (tid < 128) hsb[tid] = 0;

  // W_hh fragments: wave w tiles {w, w+8, w+16, w+24}
  bf16x8 wf[4][4];
#pragma unroll
  for (int i=0;i<4;i++){
    int nt = wave + 8*i;
#pragma unroll
    for (int ks=0; ks<4; ks++){
      bf16x8 z = {0,0,0,0,0,0,0,0};
      int k = ks*32 + lq*8;
      if (nt < 25 && k < KW)
        z = *(const bf16x8*)(whhb + (size_t)(nt*16 + lrow)*KW + k);
      wf[i][ks] = z;
    }
  }
  float c = 0.f;
  __syncthreads();

  // ---- recurrence: 20 steps ----
  for (int tt=0; tt<L_SEQ; tt++){
    bf16x8 hf[4];
#pragma unroll
    for (int ks=0; ks<4; ks++)
      hf[ks] = *(const bf16x8*)(hsb + ks*32 + lq*8);
#pragma unroll
    for (int i=0;i<4;i++){
      int nt = wave + 8*i;
      if (nt < 25){
        f32x4 acc = (f32x4){0.f,0.f,0.f,0.f};
#pragma unroll
        for (int ks=0; ks<4; ks++)
          acc = __builtin_amdgcn_mfma_f32_16x16x32_bf16(wf[i][ks], hf[ks], acc, 0, 0, 0);
        if (lrow == 0) *(f32x4*)(&gsh[nt*16 + lq*4]) = acc;
      }
    }
    __syncthreads();
    if (tid < 100){
      float g0 = gsh[tid      ] + gxl[tt][tid      ];
      float g1 = gsh[tid + 100] + gxl[tt][tid + 100];
      float g2 = gsh[tid + 200] + gxl[tt][tid + 200];
      float g3 = gsh[tid + 300] + gxl[tt][tid + 300];
      float ig = fsig(g0), fg = fsig(g1);
      float gg = ftanh(g2), og = fsig(g3);
      c = fg*c + ig*gg;
      float h = og * ftanh(c);
      hsb[tid] = f2bf(h);
      ((float*)hu4[tt])[tid] = h;
    }
    __syncthreads();
  }

  // ---- stageb (x-gates from gx rows 2048+n; W1 from LDS) ----
  int s = tid / 100, j2 = tid - s*100;
  if (tid < 500){
    int n = b*5 + s;
    ((float*)stcat4)[s*200 + j2] = user[(size_t)sn2[n]*E_DIM + j2];
    const float* gr = gx + (size_t)(2048+n)*400;
    float c0  = fsig(gr[j2]) * ftanh(gr[200+j2]);
    ((float*)stcat4)[s*200 + 100 + j2] = fsig(gr[300+j2]) * ftanh(c0);
  }
  __syncthreads();
  if (tid < 500){
    float acc = 0.f;
    const float4* w1row = Wsh + j2*WSTR;
#pragma unroll
    for (int k=0;k<50;k++) acc += dot4(w1row[k], stcat4[s][k]);
    ls2l[s][j2] = fmaxf(acc, 0.f);
  }
  __syncthreads();           // all W1 reads done

  // restage Wsh with W2 (latency hidden under GAT phases)
  {
    const float4* w2g = (const float4*)W2;           // 100 rows x 50 f4
    for (int u = tid; u < 5000; u += 512){
      int r = u / 50, cc = u - r*50;
      Wsh[r*WSTR + cc] = w2g[u];
    }
  }

  // ---- GAT -> h04 (scores wave-parallel) ----
  if (tid < 100) ns[5][tid] = ((float*)hu4[0])[tid];
  if (tid < 500) ns[s][j2] = ls2l[s][j2];
  __syncthreads();
  if (wave < 6){
    float p = 0.f;
    if (lane < 100) p = ns[5][lane] * ns[wave][lane];
    if (lane + 64 < 100) p += ns[5][lane+64] * ns[wave][lane+64];
#pragma unroll
    for (int off=32; off>0; off>>=1) p += __shfl_xor(p, off);
    if (lane == 0) wsc[wave] = p;
  }
  __syncthreads();
  if (tid == 0){
    float m=wsc[0]; for (int k=1;k<6;k++) m=fmaxf(m,wsc[k]);
    float sum=0.f;
    for (int k=0;k<6;k++){ float e_=__builtin_amdgcn_exp2f((wsc[k]-m)*1.44269504f); wsc[k]=e_; sum+=e_; }
    float inv=1.f/sum;
    for (int k=0;k<6;k++) wsc[k]*=inv;
  }
  __syncthreads();
  if (tid < 100){ float cx=0.f; for (int k=0;k<6;k++) cx += wsc[k]*ns[k][tid]; ctx[tid]=cx; }
  __syncthreads();
  if (tid < 100){
    float acc=0.f;
    for (int e=0;e<100;e++) acc += ctx[e]*Wg0[e*E_DIM + tid];
    ((float*)h04)[tid] = fmaxf(acc, 0.f);
  }
  __syncthreads();           // h04 ready AND W2 restage visible

  // ---- sr rows (mask folded; W2 from LDS), bf16, K-pad ----
  {
    int mi4 = tid >> 7;
    int jj  = tid & 127;
#pragma unroll
    for (int r=0;r<5;r++){
      int mi = r*4 + mi4;
      int m  = b*L_SEQ + mi;
      unsigned short val = 0;
      if (jj < 100){
        float acc = 0.f;
        const float4* w2row = Wsh + jj*WSTR;
#pragma unroll
        for (int k=0;k<25;k++) acc += dot4(w2row[k],    hu4[mi][k]);
#pragma unroll
        for (int k=0;k<25;k++) acc += dot4(w2row[25+k], h04[k]);
        acc *= (float)mask[m];
        val = f2bf(acc);
      }
      srb[(size_t)m*KP + jj] = val;
    }
    if (b < 48 && tid < 128) srb[(size_t)(MROWS + b)*KP + tid] = 0;
  }
}

// ---------------- E: logits = srb @ ib^T (bf16 MFMA, f32 acc) ----------------
__global__ __launch_bounds__(256) void gemm_kernel(
    const unsigned short* __restrict__ srb, const unsigned short* __restrict__ ib,
    float* __restrict__ out){
  __shared__ unsigned short As[128*KP];
  __shared__ unsigned short Bs[128*KP];
  int orig = blockIdx.x;               // 0..3759 = 8 XCD * 470
  int xcd  = orig & 7;
  int p    = orig >> 3;
  int tile_n = p >> 1;
  int tile_m = (xcd << 1) | (p & 1);
  int tid = threadIdx.x;
  const float4* Ag = (const float4*)(srb + (size_t)tile_m*128*KP);
  const float4* Bg = (const float4*)(ib  + (size_t)tile_n*128*KP);
  float4* As4=(float4*)As; float4* Bs4=(float4*)Bs;
#pragma unroll
  for (int i=0;i<8;i++){
    int chunk = i*256 + tid;
    int row = chunk >> 4;
    int cb  = (chunk & 15) << 4;
    int sw  = cb ^ ((row & 7) << 4);
    int di  = row*16 + (sw >> 4);
    As4[di] = Ag[chunk];
    Bs4[di] = Bg[chunk];
  }
  __syncthreads();
  int wave = tid >> 6, lane = tid & 63;
  int wm = (wave >> 1) << 6, wn = (wave & 1) << 6;
  int lrow = lane & 15, lq = lane >> 4;
  f32x4 acc[4][4];
#pragma unroll
  for (int i=0;i<4;i++)
#pragma unroll
    for (int jj=0;jj<4;jj++) acc[i][jj] = (f32x4){0.f,0.f,0.f,0.f};
#pragma unroll
  for (int kk=0;kk<4;kk++){
    int koffb = (kk*32 + lq*8) * 2;
    bf16x8 a[4], bfr[4];
#pragma unroll
    for (int i=0;i<4;i++){
      int row = wm + i*16 + lrow;
      int boff = koffb ^ ((row & 7) << 4);
      a[i] = *(const bf16x8*)(As + row*KP + (boff >> 1));
    }
#pragma unroll
    for (int jj=0;jj<4;jj++){
      int row = wn + jj*16 + lrow;
      int boff = koffb ^ ((row & 7) << 4);
      bfr[jj] = *(const bf16x8*)(Bs + row*KP + (boff >> 1));
    }
#pragma unroll
    for (int i=0;i<4;i++)
#pragma unroll
      for (int jj=0;jj<4;jj++)
        acc[i][jj] = __builtin_amdgcn_mfma_f32_16x16x32_bf16(bfr[jj], a[i], acc[i][jj], 0, 0, 0);
  }
  int v0 = tile_n*128 + wn + lq*4;
  int m0 = tile_m*128 + wm + lrow;
#pragma unroll
  for (int i=0;i<4;i++){
    int m = m0 + i*16;
    if (m < MROWS){
#pragma unroll
      for (int jj=0;jj<4;jj++){
        int v = v0 + jj*16;
        if (v < NV)
          *(float4*)(out + (size_t)m*NV + v) = (float4){acc[i][jj][0], acc[i][jj][1], acc[i][jj][2], acc[i][jj][3]};
      }
    }
  }
}

extern "C" void kernel_launch(void* const* d_in, const int* in_sizes, int n_in,
                              void* d_out, int out_size, void* d_ws, size_t ws_size,
                              hipStream_t stream) {
  const int*   seq  = (const int*)d_in[0];
  const int*   sn2  = (const int*)d_in[2];
  const int*   ss2  = (const int*)d_in[4];
  const int*   mask = (const int*)d_in[5];
  const float* user = (const float*)d_in[6];
  const float* item = (const float*)d_in[7];
  const float* W_ih = (const float*)d_in[8];
  const float* W_hh = (const float*)d_in[9];
  const float* b_ih = (const float*)d_in[10];
  const float* b_hh = (const float*)d_in[11];
  const float* W1   = (const float*)d_in[12];
  const float* W2   = (const float*)d_in[13];
  const float* Wg0  = (const float*)d_in[14];
  float* out = (float*)d_out;
  char* ws = (char*)d_ws;

  unsigned short* ib    = (unsigned short*)(ws);              // 7,700,480 B
  unsigned short* srb   = (unsigned short*)(ws + 7700480);    //   524,288 B
  unsigned short* xg    = (unsigned short*)(ws + 8224768);    //   655,360 B
  unsigned short* wihb  = (unsigned short*)(ws + 8880128);    //   131,072 B
  unsigned short* whhb  = (unsigned short*)(ws + 9011200);    //    89,600 B
  float*          biasv = (float*)(ws + 9100800);             //     2,048 B
  float*          gx    = (float*)(ws + 9102848);             // 4,096,000 B

  gather_kernel<<<dim3(4190), dim3(256), 0, stream>>>(
      seq, ss2, item, W_ih, W_hh, b_ih, b_hh, ib, xg, wihb, whhb, biasv);
  gxgemm_kernel<<<dim3(80), dim3(256), 0, stream>>>(xg, wihb, biasv, gx);
  // ---- amplification probe: 4 identical prep launches (idempotent) ----
  prep_kernel<<<dim3(100), dim3(512), 0, stream>>>(
      sn2, mask, user, W1, W2, Wg0, whhb, gx, srb);
  prep_kernel<<<dim3(100), dim3(512), 0, stream>>>(
      sn2, mask, user, W1, W2, Wg0, whhb, gx, srb);
  prep_kernel<<<dim3(100), dim3(512), 0, stream>>>(
      sn2, mask, user, W1, W2, Wg0, whhb, gx, srb);
  prep_kernel<<<dim3(100), dim3(512), 0, stream>>>(
      sn2, mask, user, W1, W2, Wg0, whhb, gx, srb);
  gemm_kernel<<<dim3(3760), dim3(256), 0, stream>>>(srb, ib, out);
}

// Round 13
// 101.118 us; speedup vs baseline: 1.8200x; 1.8200x over previous
//
#include <hip/hip_runtime.h>

typedef __attribute__((ext_vector_type(8))) short bf16x8;
typedef __attribute__((ext_vector_type(4))) float f32x4;
typedef __attribute__((ext_vector_type(4))) unsigned short us4;

#define E_DIM 100
#define L_SEQ 20
#define NV    30000
#define NVP   30080
#define MROWS 2000
#define KP    128
#define KW    112       // whh padded K
#define WSTR  53        // W1/W2 LDS row stride in float4

__device__ inline unsigned short f2bf(float f){
  unsigned int u = __float_as_uint(f);
  return (unsigned short)((u + 0x7fffu + ((u>>16)&1u)) >> 16);
}
__device__ inline float dot4(float4 a, float4 b){
  return a.x*b.x + a.y*b.y + a.z*b.z + a.w*b.w;
}
__device__ inline void store4bf(unsigned short* dst, float4 x){
  us4 p = { f2bf(x.x), f2bf(x.y), f2bf(x.z), f2bf(x.w) };
  *(us4*)dst = p;
}
__device__ inline float fsig(float x){
  float t = __builtin_amdgcn_exp2f(x * -1.44269504f);
  return __builtin_amdgcn_rcpf(1.f + t);
}
__device__ inline float ftanh(float x){
  float cx = fminf(fmaxf(x, -15.f), 15.f);
  float t = __builtin_amdgcn_exp2f(cx * 2.88539008f);
  return (t - 1.f) * __builtin_amdgcn_rcpf(t + 1.f);
}

// ---------------- G: build all bf16 operands + L3-warm prep's inputs ----------------
#define C1     962560
#define C2    1044480
#define C3    1060864
#define C4    1072064
#define C5    1072576
#define C6    1098076   // C5 + 25500 warming ids
__global__ void gather_kernel(const int* __restrict__ seq, const int* __restrict__ ss2,
    const int* __restrict__ sn2, const int* __restrict__ mask,
    const float* __restrict__ item, const float* __restrict__ user,
    const float* __restrict__ W_ih, const float* __restrict__ W_hh,
    const float* __restrict__ b_ih, const float* __restrict__ b_hh,
    const float* __restrict__ W1, const float* __restrict__ W2,
    const float* __restrict__ Wg0,
    unsigned short* __restrict__ ib, unsigned short* __restrict__ xg,
    unsigned short* __restrict__ wihb, unsigned short* __restrict__ whhb,
    float* __restrict__ biasv, float* __restrict__ sink){
  int id = blockIdx.x*256 + threadIdx.x;
  if (id < C1){
    int v = id >> 5, k4 = (id & 31) << 2;
    float4 x = {0.f,0.f,0.f,0.f};
    if (v < NV && k4 < 100) x = *(const float4*)(item + (size_t)v*E_DIM + k4);
    store4bf(ib + (size_t)v*KP + k4, x);
  } else if (id < C2){
    int idx = id - C1;
    int m = idx >> 5, k4 = (idx & 31) << 2;
    int src = -1;
    if (m < MROWS) src = seq[m];
    else if (m >= 2048 && m < 2548) src = ss2[(m-2048)*L_SEQ];
    float4 x = {0.f,0.f,0.f,0.f};
    if (src >= 0 && k4 < 100) x = *(const float4*)(item + (size_t)src*E_DIM + k4);
    store4bf(xg + (size_t)m*KP + k4, x);
  } else if (id < C3){
    int idx = id - C2;
    int j = idx >> 5, k4 = (idx & 31) << 2;
    float4 x = {0.f,0.f,0.f,0.f};
    if (j < 400 && k4 < 100) x = *(const float4*)(W_ih + (size_t)j*E_DIM + k4);
    store4bf(wihb + (size_t)j*KP + k4, x);
  } else if (id < C4){
    int idx = id - C3;
    int j = idx / 28, k4 = (idx - j*28) << 2;
    float4 x = {0.f,0.f,0.f,0.f};
    if (k4 < 100) x = *(const float4*)(W_hh + (size_t)j*E_DIM + k4);
    store4bf(whhb + (size_t)j*KW + k4, x);
  } else if (id < C5){
    int n = id - C4;
    biasv[n] = (n < 400) ? (b_ih[n] + b_hh[n]) : 0.f;
  } else if (id < C6){
    // ---- L3 warming: read everything prep_kernel will touch ----
    int id2 = id - C5;
    float s = 0.f;
    if (id2 < 5000){                       // W1 (80 KB)
      float4 x = ((const float4*)W1)[id2];
      s = x.x + x.y + x.z + x.w;
    } else if (id2 < 10000){               // W2 (80 KB)
      float4 x = ((const float4*)W2)[id2 - 5000];
      s = x.x + x.y + x.z + x.w;
    } else if (id2 < 12500){               // Wg0 (40 KB)
      float4 x = ((const float4*)Wg0)[id2 - 10000];
      s = x.x + x.y + x.z + x.w;
    } else if (id2 < 25000){               // user rows prep reads (500 x 400 B)
      int idx = id2 - 12500;
      int n = idx / 25, k = idx - n*25;
      float4 x = *(const float4*)(user + (size_t)sn2[n]*E_DIM + k*4);
      s = x.x + x.y + x.z + x.w;
    } else {                               // mask (8 KB)
      int4 mv = ((const int4*)mask)[id2 - 25000];
      s = (float)(mv.x + mv.y + mv.z + mv.w);
    }
    sink[id2] = s;                         // DCE-proof; sink never read
  }
}

// ---------------- GX: gx[m][n] = xg[m] . wihb[n] + biasv[n] (MFMA) ----------------
__global__ __launch_bounds__(256) void gxgemm_kernel(
    const unsigned short* __restrict__ xg, const unsigned short* __restrict__ wihb,
    const float* __restrict__ biasv, float* __restrict__ gx){
  __shared__ unsigned short As[128*KP];
  __shared__ unsigned short Bs[128*KP];
  int tile_m = blockIdx.x >> 2;
  int tile_n = blockIdx.x & 3;
  int tid = threadIdx.x;
  const float4* Ag = (const float4*)(xg   + (size_t)tile_m*128*KP);
  const float4* Bg = (const float4*)(wihb + (size_t)tile_n*128*KP);
  float4* As4=(float4*)As; float4* Bs4=(float4*)Bs;
#pragma unroll
  for (int i=0;i<8;i++){
    int chunk = i*256 + tid;
    int row = chunk >> 4;
    int cb  = (chunk & 15) << 4;
    int sw  = cb ^ ((row & 7) << 4);
    int di  = row*16 + (sw >> 4);
    As4[di] = Ag[chunk];
    Bs4[di] = Bg[chunk];
  }
  __syncthreads();
  int wave = tid >> 6, lane = tid & 63;
  int wm = (wave >> 1) << 6, wn = (wave & 1) << 6;
  int lrow = lane & 15, lq = lane >> 4;
  f32x4 acc[4][4];
#pragma unroll
  for (int i=0;i<4;i++)
#pragma unroll
    for (int jj=0;jj<4;jj++) acc[i][jj] = (f32x4){0.f,0.f,0.f,0.f};
#pragma unroll
  for (int kk=0;kk<4;kk++){
    int koffb = (kk*32 + lq*8) * 2;
    bf16x8 a[4], bfr[4];
#pragma unroll
    for (int i=0;i<4;i++){
      int row = wm + i*16 + lrow;
      int boff = koffb ^ ((row & 7) << 4);
      a[i] = *(const bf16x8*)(As + row*KP + (boff >> 1));
    }
#pragma unroll
    for (int jj=0;jj<4;jj++){
      int row = wn + jj*16 + lrow;
      int boff = koffb ^ ((row & 7) << 4);
      bfr[jj] = *(const bf16x8*)(Bs + row*KP + (boff >> 1));
    }
#pragma unroll
    for (int i=0;i<4;i++)
#pragma unroll
      for (int jj=0;jj<4;jj++)
        acc[i][jj] = __builtin_amdgcn_mfma_f32_16x16x32_bf16(bfr[jj], a[i], acc[i][jj], 0, 0, 0);
  }
  int n0 = tile_n*128 + wn + lq*4;
  int m0 = tile_m*128 + wm + lrow;
#pragma unroll
  for (int i=0;i<4;i++){
    int m = m0 + i*16;
#pragma unroll
    for (int jj=0;jj<4;jj++){
      int n = n0 + jj*16;
      if (n < 400){
        float4 bv = *(const float4*)(biasv + n);
        *(float4*)(gx + (size_t)m*400 + n) =
          (float4){acc[i][jj][0]+bv.x, acc[i][jj][1]+bv.y, acc[i][jj][2]+bv.z, acc[i][jj][3]+bv.w};
      }
    }
  }
}

// ---------------- PREP (R10 exact): MFMA recurrence; W1/W2 LDS-staged ----------
__global__ __launch_bounds__(512,1) void prep_kernel(
    const int* __restrict__ sn2, const int* __restrict__ mask,
    const float* __restrict__ user, const float* __restrict__ W1,
    const float* __restrict__ W2, const float* __restrict__ Wg0,
    const unsigned short* __restrict__ whhb, const float* __restrict__ gx,
    unsigned short* __restrict__ srb){
  int b = blockIdx.x, tid = threadIdx.x;
  int wave = tid >> 6, lane = tid & 63;
  int lrow = lane & 15, lq = lane >> 4;
  __shared__ float4 Wsh[100*WSTR];       // 84,800 B: W1, then W2 (restaged)
  __shared__ float  gxl[L_SEQ][400];     // 32,000 B
  __shared__ unsigned short hsb[128];
  __shared__ float  gsh[400];
  __shared__ float4 hu4[L_SEQ][25];
  __shared__ float4 stcat4[5][50];
  __shared__ float  ls2l[5][100];
  __shared__ float  ns[6][100];
  __shared__ float  wsc[8];
  __shared__ float  ctx[100];
  __shared__ float4 h04[25];

  // stage gx rows for this block (2000 float4, coalesced) + W1 -> LDS
  {
    const float4* src = (const float4*)(gx + (size_t)b*L_SEQ*400);
    for (int u = tid; u < 2000; u += 512) ((float4*)gxl)[u] = src[u];
    const float4* w1g = (const float4*)W1;           // 100 rows x 50 f4
    for (int u = tid; u < 5000; u += 512){
      int r = u / 50, cc = u - r*50;
      Wsh[r*WSTR + cc] = w1g[u];
    }
  }
  if (tid < 128) hsb[tid] = 0;

  // W_hh fragments: wave w tiles {w, w+8, w+16, w+24}
  bf16x8 wf[4][4];
#pragma unroll
  for (int i=0;i<4;i++){
    int nt = wave + 8*i;
#pragma unroll
    for (int ks=0; ks<4; ks++){
      bf16x8 z = {0,0,0,0,0,0,0,0};
      int k = ks*32 + lq*8;
      if (nt < 25 && k < KW)
        z = *(const bf16x8*)(whhb + (size_t)(nt*16 + lrow)*KW + k);
      wf[i][ks] = z;
    }
  }
  float c = 0.f;
  __syncthreads();

  // ---- recurrence: 20 steps ----
  for (int tt=0; tt<L_SEQ; tt++){
    bf16x8 hf[4];
#pragma unroll
    for (int ks=0; ks<4; ks++)
      hf[ks] = *(const bf16x8*)(hsb + ks*32 + lq*8);
#pragma unroll
    for (int i=0;i<4;i++){
      int nt = wave + 8*i;
      if (nt < 25){
        f32x4 acc = (f32x4){0.f,0.f,0.f,0.f};
#pragma unroll
        for (int ks=0; ks<4; ks++)
          acc = __builtin_amdgcn_mfma_f32_16x16x32_bf16(wf[i][ks], hf[ks], acc, 0, 0, 0);
        if (lrow == 0) *(f32x4*)(&gsh[nt*16 + lq*4]) = acc;
      }
    }
    __syncthreads();
    if (tid < 100){
      float g0 = gsh[tid      ] + gxl[tt][tid      ];
      float g1 = gsh[tid + 100] + gxl[tt][tid + 100];
      float g2 = gsh[tid + 200] + gxl[tt][tid + 200];
      float g3 = gsh[tid + 300] + gxl[tt][tid + 300];
      float ig = fsig(g0), fg = fsig(g1);
      float gg = ftanh(g2), og = fsig(g3);
      c = fg*c + ig*gg;
      float h = og * ftanh(c);
      hsb[tid] = f2bf(h);
      ((float*)hu4[tt])[tid] = h;
    }
    __syncthreads();
  }

  // ---- stageb (x-gates from gx rows 2048+n; W1 from LDS) ----
  int s = tid / 100, j2 = tid - s*100;
  if (tid < 500){
    int n = b*5 + s;
    ((float*)stcat4)[s*200 + j2] = user[(size_t)sn2[n]*E_DIM + j2];
    const float* gr = gx + (size_t)(2048+n)*400;
    float c0  = fsig(gr[j2]) * ftanh(gr[200+j2]);
    ((float*)stcat4)[s*200 + 100 + j2] = fsig(gr[300+j2]) * ftanh(c0);
  }
  __syncthreads();
  if (tid < 500){
    float acc = 0.f;
    const float4* w1row = Wsh + j2*WSTR;
#pragma unroll
    for (int k=0;k<50;k++) acc += dot4(w1row[k], stcat4[s][k]);
    ls2l[s][j2] = fmaxf(acc, 0.f);
  }
  __syncthreads();           // all W1 reads done

  // restage Wsh with W2 (latency hidden under GAT phases)
  {
    const float4* w2g = (const float4*)W2;           // 100 rows x 50 f4
    for (int u = tid; u < 5000; u += 512){
      int r = u / 50, cc = u - r*50;
      Wsh[r*WSTR + cc] = w2g[u];
    }
  }

  // ---- GAT -> h04 (scores wave-parallel) ----
  if (tid < 100) ns[5][tid] = ((float*)hu4[0])[tid];
  if (tid < 500) ns[s][j2] = ls2l[s][j2];
  __syncthreads();
  if (wave < 6){
    float p = 0.f;
    if (lane < 100) p = ns[5][lane] * ns[wave][lane];
    if (lane + 64 < 100) p += ns[5][lane+64] * ns[wave][lane+64];
#pragma unroll
    for (int off=32; off>0; off>>=1) p += __shfl_xor(p, off);
    if (lane == 0) wsc[wave] = p;
  }
  __syncthreads();
  if (tid == 0){
    float m=wsc[0]; for (int k=1;k<6;k++) m=fmaxf(m,wsc[k]);
    float sum=0.f;
    for (int k=0;k<6;k++){ float e_=__builtin_amdgcn_exp2f((wsc[k]-m)*1.44269504f); wsc[k]=e_; sum+=e_; }
    float inv=1.f/sum;
    for (int k=0;k<6;k++) wsc[k]*=inv;
  }
  __syncthreads();
  if (tid < 100){ float cx=0.f; for (int k=0;k<6;k++) cx += wsc[k]*ns[k][tid]; ctx[tid]=cx; }
  __syncthreads();
  if (tid < 100){
    float acc=0.f;
    for (int e=0;e<100;e++) acc += ctx[e]*Wg0[e*E_DIM + tid];
    ((float*)h04)[tid] = fmaxf(acc, 0.f);
  }
  __syncthreads();           // h04 ready AND W2 restage visible

  // ---- sr rows (mask folded; W2 from LDS), bf16, K-pad ----
  {
    int mi4 = tid >> 7;
    int jj  = tid & 127;
#pragma unroll
    for (int r=0;r<5;r++){
      int mi = r*4 + mi4;
      int m  = b*L_SEQ + mi;
      unsigned short val = 0;
      if (jj < 100){
        float acc = 0.f;
        const float4* w2row = Wsh + jj*WSTR;
#pragma unroll
        for (int k=0;k<25;k++) acc += dot4(w2row[k],    hu4[mi][k]);
#pragma unroll
        for (int k=0;k<25;k++) acc += dot4(w2row[25+k], h04[k]);
        acc *= (float)mask[m];
        val = f2bf(acc);
      }
      srb[(size_t)m*KP + jj] = val;
    }
    if (b < 48 && tid < 128) srb[(size_t)(MROWS + b)*KP + tid] = 0;
  }
}

// ---------------- E: logits = srb @ ib^T (bf16 MFMA, f32 acc) ----------------
__global__ __launch_bounds__(256) void gemm_kernel(
    const unsigned short* __restrict__ srb, const unsigned short* __restrict__ ib,
    float* __restrict__ out){
  __shared__ unsigned short As[128*KP];
  __shared__ unsigned short Bs[128*KP];
  int orig = blockIdx.x;               // 0..3759 = 8 XCD * 470
  int xcd  = orig & 7;
  int p    = orig >> 3;
  int tile_n = p >> 1;
  int tile_m = (xcd << 1) | (p & 1);
  int tid = threadIdx.x;
  const float4* Ag = (const float4*)(srb + (size_t)tile_m*128*KP);
  const float4* Bg = (const float4*)(ib  + (size_t)tile_n*128*KP);
  float4* As4=(float4*)As; float4* Bs4=(float4*)Bs;
#pragma unroll
  for (int i=0;i<8;i++){
    int chunk = i*256 + tid;
    int row = chunk >> 4;
    int cb  = (chunk & 15) << 4;
    int sw  = cb ^ ((row & 7) << 4);
    int di  = row*16 + (sw >> 4);
    As4[di] = Ag[chunk];
    Bs4[di] = Bg[chunk];
  }
  __syncthreads();
  int wave = tid >> 6, lane = tid & 63;
  int wm = (wave >> 1) << 6, wn = (wave & 1) << 6;
  int lrow = lane & 15, lq = lane >> 4;
  f32x4 acc[4][4];
#pragma unroll
  for (int i=0;i<4;i++)
#pragma unroll
    for (int jj=0;jj<4;jj++) acc[i][jj] = (f32x4){0.f,0.f,0.f,0.f};
#pragma unroll
  for (int kk=0;kk<4;kk++){
    int koffb = (kk*32 + lq*8) * 2;
    bf16x8 a[4], bfr[4];
#pragma unroll
    for (int i=0;i<4;i++){
      int row = wm + i*16 + lrow;
      int boff = koffb ^ ((row & 7) << 4);
      a[i] = *(const bf16x8*)(As + row*KP + (boff >> 1));
    }
#pragma unroll
    for (int jj=0;jj<4;jj++){
      int row = wn + jj*16 + lrow;
      int boff = koffb ^ ((row & 7) << 4);
      bfr[jj] = *(const bf16x8*)(Bs + row*KP + (boff >> 1));
    }
#pragma unroll
    for (int i=0;i<4;i++)
#pragma unroll
      for (int jj=0;jj<4;jj++)
        acc[i][jj] = __builtin_amdgcn_mfma_f32_16x16x32_bf16(bfr[jj], a[i], acc[i][jj], 0, 0, 0);
  }
  int v0 = tile_n*128 + wn + lq*4;
  int m0 = tile_m*128 + wm + lrow;
#pragma unroll
  for (int i=0;i<4;i++){
    int m = m0 + i*16;
    if (m < MROWS){
#pragma unroll
      for (int jj=0;jj<4;jj++){
        int v = v0 + jj*16;
        if (v < NV)
          *(float4*)(out + (size_t)m*NV + v) = (float4){acc[i][jj][0], acc[i][jj][1], acc[i][jj][2], acc[i][jj][3]};
      }
    }
  }
}

extern "C" void kernel_launch(void* const* d_in, const int* in_sizes, int n_in,
                              void* d_out, int out_size, void* d_ws, size_t ws_size,
                              hipStream_t stream) {
  const int*   seq  = (const int*)d_in[0];
  const int*   sn2  = (const int*)d_in[2];
  const int*   ss2  = (const int*)d_in[4];
  const int*   mask = (const int*)d_in[5];
  const float* user = (const float*)d_in[6];
  const float* item = (const float*)d_in[7];
  const float* W_ih = (const float*)d_in[8];
  const float* W_hh = (const float*)d_in[9];
  const float* b_ih = (const float*)d_in[10];
  const float* b_hh = (const float*)d_in[11];
  const float* W1   = (const float*)d_in[12];
  const float* W2   = (const float*)d_in[13];
  const float* Wg0  = (const float*)d_in[14];
  float* out = (float*)d_out;
  char* ws = (char*)d_ws;

  unsigned short* ib    = (unsigned short*)(ws);              // 7,700,480 B
  unsigned short* srb   = (unsigned short*)(ws + 7700480);    //   524,288 B
  unsigned short* xg    = (unsigned short*)(ws + 8224768);    //   655,360 B
  unsigned short* wihb  = (unsigned short*)(ws + 8880128);    //   131,072 B
  unsigned short* whhb  = (unsigned short*)(ws + 9011200);    //    89,600 B
  float*          biasv = (float*)(ws + 9100800);             //     2,048 B
  float*          gx    = (float*)(ws + 9102848);             // 4,096,000 B
  float*          sink  = (float*)(ws + 13198848);            //   102,000 B (warming sink)

  gather_kernel<<<dim3(4290), dim3(256), 0, stream>>>(
      seq, ss2, sn2, mask, item, user, W_ih, W_hh, b_ih, b_hh, W1, W2, Wg0,
      ib, xg, wihb, whhb, biasv, sink);
  gxgemm_kernel<<<dim3(80), dim3(256), 0, stream>>>(xg, wihb, biasv, gx);
  prep_kernel<<<dim3(100), dim3(512), 0, stream>>>(
      sn2, mask, user, W1, W2, Wg0, whhb, gx, srb);
  gemm_kernel<<<dim3(3760), dim3(256), 0, stream>>>(srb, ib, out);
}